// Round 14
// baseline (716.321 us; speedup 1.0000x reference)
//
#include <hip/hip_runtime.h>

#define N_NODES 30000
#define N_EDGES 300000
#define NUM_GRAPHS 512
#define HID 600
#define IN_FEATS 9
#define NUM_TASKS 128

#define MPAD 30208          // 118 * 256 = 236 * 128
#define HPAD 640
#define K0PAD 32

typedef __attribute__((ext_vector_type(4))) float f32x4;
typedef __attribute__((ext_vector_type(8))) short bf16x8;

// ---------------- bf16 helpers ----------------

__device__ __forceinline__ float bflo(unsigned int v) {
  union { unsigned int u; float f; } c; c.u = v << 16; return c.f;
}
__device__ __forceinline__ float bfhi(unsigned int v) {
  union { unsigned int u; float f; } c; c.u = v & 0xffff0000u; return c.f;
}
__device__ __forceinline__ unsigned short f2bf(float f) {
  union { float f; unsigned int u; } c; c.f = f;
  unsigned int u = c.u;
  return (unsigned short)((u + 0x7fffu + ((u >> 16) & 1u)) >> 16);
}
__device__ __forceinline__ unsigned int pack2(float a, float b) {
  return (unsigned int)f2bf(a) | ((unsigned int)f2bf(b) << 16);
}

// ---------------- fused setup ----------------

__global__ void k_setup(const float* __restrict__ w1_0,
                        const float* __restrict__ b1_0, const float* __restrict__ b2_0,
                        const float* __restrict__ b1_r, const float* __restrict__ b2_r,
                        const float* __restrict__ x,
                        const int* __restrict__ e_dst, const int* __restrict__ batch,
                        unsigned short* __restrict__ wt0, float* __restrict__ biases,
                        unsigned short* __restrict__ xb,
                        int* __restrict__ counts, int* __restrict__ gcnt) {
  const int S0 = HPAD * K0PAD;
  const int S1 = 10 * HPAD;
  const int S2 = MPAD * K0PAD;
  const int S3 = N_EDGES;
  int idx = blockIdx.x * 256 + threadIdx.x;
  if (idx < S0) {
    int n = idx / K0PAD, k = idx % K0PAD;
    float v = (n < HID && k < IN_FEATS) ? w1_0[(size_t)k * HID + n] : 0.f;
    wt0[idx] = f2bf(v);
    return;
  }
  idx -= S0;
  if (idx < S1) {
    int w = idx / HPAD, i = idx % HPAD;
    float v = 0.f;
    if (i < HID) {
      if (w == 0) v = b1_0[i];
      else if (w == 1) v = b2_0[i];
      else if (w < 6) v = b1_r[(size_t)(w - 2) * HID + i];
      else v = b2_r[(size_t)(w - 6) * HID + i];
    }
    biases[idx] = v;
    return;
  }
  idx -= S1;
  if (idx < S2) {
    int m = idx >> 5, k = idx & 31;
    float v = (m < N_NODES && k < IN_FEATS) ? x[(size_t)m * IN_FEATS + k] : 0.f;
    xb[idx] = f2bf(v);
    return;
  }
  idx -= S2;
  if (idx < S3) {
    atomicAdd(&counts[e_dst[idx]], 1);
    return;
  }
  idx -= S3;
  if (idx < N_NODES) {
    atomicAdd(&gcnt[batch[idx]], 1);
  }
}

// ---------------- CSR scan ----------------

__global__ __launch_bounds__(1024) void k_exscan(const int* __restrict__ in,
                                                 int* __restrict__ out,
                                                 int* cursor, int n) {
  __shared__ int buf[1024];
  int tid = threadIdx.x;
  int CH = (n + 1023) / 1024;
  int base = tid * CH;
  int s = 0;
  for (int j = 0; j < CH; ++j) {
    int i = base + j;
    if (i < n) s += in[i];
  }
  buf[tid] = s;
  __syncthreads();
  for (int off = 1; off < 1024; off <<= 1) {
    int t = (tid >= off) ? buf[tid - off] : 0;
    __syncthreads();
    buf[tid] += t;
    __syncthreads();
  }
  int pre = (tid == 0) ? 0 : buf[tid - 1];
  for (int j = 0; j < CH; ++j) {
    int i = base + j;
    if (i <= n) out[i] = pre;
    if (i < n) {
      int v = in[i];
      if (cursor) cursor[i] = pre;
      pre += v;
    }
  }
}

__global__ __launch_bounds__(256) void k_scan1(const int* __restrict__ in,
                                               int* __restrict__ partials, int n) {
  __shared__ int buf[256];
  int i = blockIdx.x * 256 + threadIdx.x;
  buf[threadIdx.x] = (i < n) ? in[i] : 0;
  __syncthreads();
  for (int off = 128; off; off >>= 1) {
    if (threadIdx.x < off) buf[threadIdx.x] += buf[threadIdx.x + off];
    __syncthreads();
  }
  if (threadIdx.x == 0) partials[blockIdx.x] = buf[0];
}

__global__ __launch_bounds__(256) void k_scan3(const int* __restrict__ in,
                                               const int* __restrict__ poff,
                                               int* __restrict__ out,
                                               int* __restrict__ cursor, int n) {
  __shared__ int buf[256];
  int b = blockIdx.x, t = threadIdx.x;
  int i = b * 256 + t;
  int v = (i < n) ? in[i] : 0;
  buf[t] = v;
  __syncthreads();
  for (int off = 1; off < 256; off <<= 1) {
    int x = (t >= off) ? buf[t - off] : 0;
    __syncthreads();
    buf[t] += x;
    __syncthreads();
  }
  int base = poff[b];
  int excl = base + buf[t] - v;
  if (i < n) {
    out[i] = excl;
    cursor[i] = excl;
    if (i == n - 1) out[n] = base + buf[t];
  }
}

__global__ void k_scatter(const int* __restrict__ src, const int* __restrict__ dst,
                          int* __restrict__ cursor, int* __restrict__ edge_src, int E) {
  int e = blockIdx.x * blockDim.x + threadIdx.x;
  if (e < E) {
    int pos = atomicAdd(&cursor[dst[e]], 1);
    edge_src[pos] = src[e];
  }
}

// ---------------- big-weight transpose ----------------

__global__ __launch_bounds__(256) void k_wt_tiled(
    const float* __restrict__ w2_0, const float* __restrict__ w1_r,
    const float* __restrict__ w2_r, unsigned short* __restrict__ wts) {
  __shared__ float tile[64][65];
  int b = blockIdx.x;
  int w = b / 100;
  int tb = b % 100;
  int tn = (tb % 10) * 64;
  int tk = (tb / 10) * 64;
  const float* W;
  if (w == 0) W = w2_0;
  else if (w < 5) W = w1_r + (size_t)(w - 1) * HID * HID;
  else W = w2_r + (size_t)(w - 5) * HID * HID;
  int t = threadIdx.x;
  int lx = t & 63, ly = t >> 6;
#pragma unroll
  for (int i = 0; i < 16; ++i) {
    int k = tk + ly + i * 4;
    int n = tn + lx;
    float v = (k < HID && n < HID) ? W[(size_t)k * HID + n] : 0.f;
    tile[ly + i * 4][lx] = v;
  }
  __syncthreads();
  unsigned short* dst = wts + (size_t)w * HPAD * HPAD;
#pragma unroll
  for (int i = 0; i < 16; ++i) {
    int n = tn + ly + i * 4;
    int k = tk + lx;
    dst[(size_t)n * HPAD + k] = f2bf(tile[lx][ly + i * 4]);
  }
}

// ---------------- aggregation ----------------

template <int U>
__global__ __launch_bounds__(256) void k_agg_bf16(
    const unsigned int* __restrict__ h, const int* __restrict__ ptr,
    const int* __restrict__ esrc, unsigned int* __restrict__ z, int n_nodes) {
  int wave = threadIdx.x >> 6, lane = threadIdx.x & 63;
  int node = blockIdx.x * 4 + wave;
  if (node >= n_nodes) return;
  int beg = ptr[node], end = ptr[node + 1];
  const unsigned int* hn = h + (size_t)node * U;
  float a0[5], a1[5];
#pragma unroll
  for (int i = 0; i < 5; ++i) {
    int u = lane + i * 64;
    if (u < U) { unsigned int v = hn[u]; a0[i] = bflo(v); a1[i] = bfhi(v); }
    else { a0[i] = 0.f; a1[i] = 0.f; }
  }
  int e = beg;
  for (; e + 4 <= end; e += 4) {
    const unsigned int* p0 = h + (size_t)esrc[e] * U;
    const unsigned int* p1 = h + (size_t)esrc[e + 1] * U;
    const unsigned int* p2 = h + (size_t)esrc[e + 2] * U;
    const unsigned int* p3 = h + (size_t)esrc[e + 3] * U;
    unsigned int v0[5], v1[5], v2[5], v3[5];
#pragma unroll
    for (int i = 0; i < 5; ++i) {
      int u = lane + i * 64;
      if (u < U) { v0[i] = p0[u]; v1[i] = p1[u]; v2[i] = p2[u]; v3[i] = p3[u]; }
      else { v0[i] = 0; v1[i] = 0; v2[i] = 0; v3[i] = 0; }
    }
#pragma unroll
    for (int i = 0; i < 5; ++i) {
      a0[i] += (bflo(v0[i]) + bflo(v1[i])) + (bflo(v2[i]) + bflo(v3[i]));
      a1[i] += (bfhi(v0[i]) + bfhi(v1[i])) + (bfhi(v2[i]) + bfhi(v3[i]));
    }
  }
  for (; e < end; ++e) {
    const unsigned int* p0 = h + (size_t)esrc[e] * U;
#pragma unroll
    for (int i = 0; i < 5; ++i) {
      int u = lane + i * 64;
      if (u < U) { unsigned int v = p0[u]; a0[i] += bflo(v); a1[i] += bfhi(v); }
    }
  }
  unsigned int* zn = z + (size_t)node * U;
#pragma unroll
  for (int i = 0; i < 5; ++i) {
    int u = lane + i * 64;
    if (u < U) zn[u] = pack2(a0[i], a1[i]);
  }
}

// ---------------- GEMM control (R13 best): 128x128, 8 waves, 24 waves/CU ----------------

#define GLOAD(gptr, lptr)                                                            \
  __builtin_amdgcn_global_load_lds(                                                  \
      (const __attribute__((address_space(1))) unsigned int*)(gptr),                 \
      (__attribute__((address_space(3))) unsigned int*)(lptr), 16, 0, 0)

__global__ __launch_bounds__(512, 6) void k_mgemm(
    const unsigned short* __restrict__ A, const unsigned short* __restrict__ Bt,
    const float* __restrict__ bias, unsigned short* __restrict__ C,
    int lda, int ldb, int ldc, int K, int relu, int gy) {
  int G = gridDim.x;
  int orig = blockIdx.x;
  int q = G >> 3, r = G & 7;
  int xcd = orig & 7, local = orig >> 3;
  int wgid = (xcd < r ? xcd * (q + 1) : r * (q + 1) + (xcd - r) * q) + local;
  int n0 = (wgid % gy) * 128;
  int m0 = (wgid / gy) * 128;

  __shared__ unsigned short smem[3 * 4096 * 2];
  unsigned short* Asb = smem;
  unsigned short* Bsb = smem + 12288;

  int t = threadIdx.x;
  int lane = t & 63, wave = t >> 6;
  int wm = (wave >> 2) * 64;
  int wn = (wave & 3) * 32;

  f32x4 acc[4][2] = {};

  int off = t * 8;
  int rm = off >> 5, rk = off & 31;

  const unsigned short* Ar = A + (size_t)(m0 + rm) * lda + rk;
  const unsigned short* Br = Bt + (size_t)(n0 + rm) * ldb + rk;

  int nt = K >> 5;
  GLOAD(Ar, Asb + off);
  GLOAD(Br, Bsb + off);
  if (nt > 1) {
    GLOAD(Ar + 32, Asb + 4096 + off);
    GLOAD(Br + 32, Bsb + 4096 + off);
  }

  int kk = (lane >> 4) * 8;
  int ra = wm + (lane & 15);
  int rb = wn + (lane & 15);
  int cur = 0;

  for (int tt = 0; tt < nt; ++tt) {
    if (tt + 1 < nt) {
      asm volatile("s_waitcnt vmcnt(2)" ::: "memory");
    } else {
      asm volatile("s_waitcnt vmcnt(0)" ::: "memory");
    }
    __builtin_amdgcn_s_barrier();
    if (tt + 2 < nt) {
      int k2 = (tt + 2) << 5;
      int nb = cur + 2; if (nb >= 3) nb -= 3;
      GLOAD(Ar + k2, Asb + nb * 4096 + off);
      GLOAD(Br + k2, Bsb + nb * 4096 + off);
    }
    bf16x8 a[4], b[2];
#pragma unroll
    for (int i = 0; i < 4; ++i)
      a[i] = *(const bf16x8*)(Asb + cur * 4096 + (ra + i * 16) * 32 + kk);
#pragma unroll
    for (int j = 0; j < 2; ++j)
      b[j] = *(const bf16x8*)(Bsb + cur * 4096 + (rb + j * 16) * 32 + kk);
#pragma unroll
    for (int i = 0; i < 4; ++i)
#pragma unroll
      for (int j = 0; j < 2; ++j)
        acc[i][j] = __builtin_amdgcn_mfma_f32_16x16x32_bf16(b[j], a[i], acc[i][j], 0, 0, 0);
    cur += 1; if (cur >= 3) cur = 0;
  }

  __syncthreads();
  int colm = lane & 15;
  int nq = (lane >> 4) * 4;
#pragma unroll
  for (int j = 0; j < 2; ++j) {
    int nloc = wn + j * 16 + nq;
    f32x4 bv = *(const f32x4*)&bias[n0 + nloc];
#pragma unroll
    for (int i = 0; i < 4; ++i) {
      int mloc = wm + i * 16 + colm;
      float v0 = acc[i][j][0] + bv[0];
      float v1 = acc[i][j][1] + bv[1];
      float v2 = acc[i][j][2] + bv[2];
      float v3 = acc[i][j][3] + bv[3];
      if (relu) {
        v0 = fmaxf(v0, 0.f); v1 = fmaxf(v1, 0.f);
        v2 = fmaxf(v2, 0.f); v3 = fmaxf(v3, 0.f);
      }
      uint2 w;
      w.x = pack2(v0, v1);
      w.y = pack2(v2, v3);
      int nblk = (nloc >> 2) ^ ((mloc & 7) << 2);
      *(uint2*)&smem[mloc * 128 + nblk * 4] = w;
    }
  }
  __syncthreads();
#pragma unroll
  for (int p = 0; p < 4; ++p) {
    int idx = p * 4096 + t * 8;
    int mloc = idx >> 7;
    int ncol = idx & 127;
    int s = (mloc & 7) << 2;
    int nb0 = (ncol >> 2) ^ s;
    int nb1 = ((ncol >> 2) + 1) ^ s;
    uint2 w0 = *(uint2*)&smem[mloc * 128 + nb0 * 4];
    uint2 w1 = *(uint2*)&smem[mloc * 128 + nb1 * 4];
    uint4 w;
    w.x = w0.x; w.y = w0.y; w.z = w1.x; w.w = w1.y;
    *(uint4*)&C[(size_t)(m0 + mloc) * ldc + n0 + ncol] = w;
  }
}

// ---------------- GEMM wide variant: 128 x 640 (full N), 236 blocks, 8 waves ----------------
// per-wave 64x160 (acc 4x10 f32x4), 3-stage counted vmcnt(6), read-XOR swizzle.

__global__ __launch_bounds__(512, 2) void k_mgemm_wide(
    const unsigned short* __restrict__ A, const unsigned short* __restrict__ Bt,
    const float* __restrict__ bias, unsigned short* __restrict__ C,
    int lda, int ldb, int ldc, int K, int relu) {
  int m0 = blockIdx.x * 128;

  __shared__ unsigned short smem[3 * 24576];   // 144 KB: per stage A 4096 | B 20480
  int t = threadIdx.x;
  int lane = t & 63, wave = t >> 6;
  int wm = (wave >> 2) * 64;     // 2 m-groups
  int wn = (wave & 3) * 160;     // 4 n-groups

  f32x4 acc[4][10] = {};

  int rm = t >> 2, rk = (t & 3) * 8;
  int rksrc = (((rk >> 3) ^ (rm & 3)) & 3) << 3;    // source-side pre-swizzle
  const unsigned short* Ar = A + (size_t)(m0 + rm) * lda + rksrc;
  const unsigned short* Br0 = Bt + (size_t)(rm) * ldb + rksrc;

  int nt = K >> 5;

#define WSTAGE(buf, koff)                                                  \
  do {                                                                     \
    GLOAD(Ar + (koff), smem + (buf) * 24576 + t * 8);                      \
    _Pragma("unroll")                                                      \
    for (int c = 0; c < 5; ++c)                                            \
      GLOAD(Br0 + (size_t)(c) * 128 * ldb + (koff),                        \
            smem + (buf) * 24576 + 4096 + c * 4096 + t * 8);               \
  } while (0)

  WSTAGE(0, 0);
  if (nt > 1) WSTAGE(1, 32);

  int qq = lane >> 4;
  int ra = wm + (lane & 15);
  int rb = wn + (lane & 15);
  int kka = ((qq ^ (ra & 3)) & 3) << 3;   // read-side XOR (rows of a fragment differ by 16 -> same &3)
  int kkb = ((qq ^ (rb & 3)) & 3) << 3;
  int cur = 0;

  for (int tt = 0; tt < nt; ++tt) {
    if (tt + 1 < nt) {
      asm volatile("s_waitcnt vmcnt(6)" ::: "memory");
    } else {
      asm volatile("s_waitcnt vmcnt(0)" ::: "memory");
    }
    __builtin_amdgcn_s_barrier();
    if (tt + 2 < nt) {
      int nb = cur + 2; if (nb >= 3) nb -= 3;
      WSTAGE(nb, (tt + 2) << 5);
    }
    const unsigned short* Ab = smem + cur * 24576;
    const unsigned short* Bb = smem + cur * 24576 + 4096;
    bf16x8 a[4];
#pragma unroll
    for (int i = 0; i < 4; ++i)
      a[i] = *(const bf16x8*)(Ab + (ra + i * 16) * 32 + kka);
#pragma unroll
    for (int jh = 0; jh < 2; ++jh) {
      bf16x8 b[5];
#pragma unroll
      for (int jj = 0; jj < 5; ++jj)
        b[jj] = *(const bf16x8*)(Bb + (rb + (jh * 5 + jj) * 16) * 32 + kkb);
#pragma unroll
      for (int i = 0; i < 4; ++i)
#pragma unroll
        for (int jj = 0; jj < 5; ++jj)
          acc[i][jh * 5 + jj] =
              __builtin_amdgcn_mfma_f32_16x16x32_bf16(b[jj], a[i], acc[i][jh * 5 + jj], 0, 0, 0);
    }
    cur += 1; if (cur >= 3) cur = 0;
  }

  // epilogue: direct packed stores (lane holds 4 consecutive n per fragment)
  int colm = lane & 15;
  int nq4 = qq * 4;
#pragma unroll
  for (int j = 0; j < 10; ++j) {
    int nloc = wn + j * 16 + nq4;
    f32x4 bv = *(const f32x4*)&bias[nloc];
#pragma unroll
    for (int i = 0; i < 4; ++i) {
      int m = m0 + wm + i * 16 + colm;
      float v0 = acc[i][j][0] + bv[0];
      float v1 = acc[i][j][1] + bv[1];
      float v2 = acc[i][j][2] + bv[2];
      float v3 = acc[i][j][3] + bv[3];
      if (relu) {
        v0 = fmaxf(v0, 0.f); v1 = fmaxf(v1, 0.f);
        v2 = fmaxf(v2, 0.f); v3 = fmaxf(v3, 0.f);
      }
      uint2 w;
      w.x = pack2(v0, v1);
      w.y = pack2(v2, v3);
      *(uint2*)&C[(size_t)m * ldc + nloc] = w;
    }
  }
#undef WSTAGE
}

// ---------------- fused pool + classifier ----------------

__global__ __launch_bounds__(256) void k_poolcls(
    const unsigned int* __restrict__ h, const int* __restrict__ gptr,
    const float* __restrict__ cw1, const float* __restrict__ cb1,
    const float* __restrict__ cw2, const float* __restrict__ cb2,
    const float* __restrict__ cw3, const float* __restrict__ cb3,
    float* __restrict__ out) {
  const int U = HPAD / 2;
  __shared__ float red[4][HPAD];
  __shared__ float f[HPAD];
  __shared__ float red2[4][256];
  __shared__ float z1[256];
  __shared__ float z2[256];
  int g = blockIdx.x;
  int t = threadIdx.x;
  int wave = t >> 6, lane = t & 63;
  int beg = gptr[g], end = gptr[g + 1];

  {
    float a0[5] = {0.f, 0.f, 0.f, 0.f, 0.f}, a1[5] = {0.f, 0.f, 0.f, 0.f, 0.f};
    for (int i = beg + wave; i < end; i += 4) {
      const unsigned int* hi = h + (size_t)i * U;
#pragma unroll
      for (int j = 0; j < 5; ++j) {
        unsigned int v = hi[lane + j * 64];
        a0[j] += bflo(v); a1[j] += bfhi(v);
      }
    }
#pragma unroll
    for (int j = 0; j < 5; ++j) {
      int u = lane + j * 64;
      red[wave][2 * u] = a0[j];
      red[wave][2 * u + 1] = a1[j];
    }
  }
  __syncthreads();
  for (int c = t; c < HPAD; c += 256)
    f[c] = red[0][c] + red[1][c] + red[2][c] + red[3][c];
  __syncthreads();

  {
    float acc[4] = {0.f, 0.f, 0.f, 0.f};
    int k0 = wave * 150, k1 = k0 + 150;
    for (int k = k0; k < k1; ++k) {
      float fv = f[k];
      const float* row = cw1 + (size_t)k * 256;
#pragma unroll
      for (int j = 0; j < 4; ++j) acc[j] += fv * row[lane + j * 64];
    }
#pragma unroll
    for (int j = 0; j < 4; ++j) red2[wave][lane + j * 64] = acc[j];
  }
  __syncthreads();
  z1[t] = fmaxf(red2[0][t] + red2[1][t] + red2[2][t] + red2[3][t] + cb1[t], 0.f);
  __syncthreads();

  {
    float acc[4] = {0.f, 0.f, 0.f, 0.f};
    int k0 = wave * 64, k1 = k0 + 64;
    for (int k = k0; k < k1; ++k) {
      float zv = z1[k];
      const float* row = cw2 + (size_t)k * 256;
#pragma unroll
      for (int j = 0; j < 4; ++j) acc[j] += zv * row[lane + j * 64];
    }
    __syncthreads();
#pragma unroll
    for (int j = 0; j < 4; ++j) red2[wave][lane + j * 64] = acc[j];
  }
  __syncthreads();
  z2[t] = fmaxf(red2[0][t] + red2[1][t] + red2[2][t] + red2[3][t] + cb2[t], 0.f);
  __syncthreads();

  {
    float a0 = 0.f, a1 = 0.f;
    int k0 = wave * 64, k1 = k0 + 64;
    for (int k = k0; k < k1; ++k) {
      float zv = z2[k];
      const float* row = cw3 + (size_t)k * NUM_TASKS;
      a0 += zv * row[lane];
      a1 += zv * row[lane + 64];
    }
    __syncthreads();
    red2[wave][lane] = a0;
    red2[wave][lane + 64] = a1;
  }
  __syncthreads();
  if (t < NUM_TASKS)
    out[(size_t)g * NUM_TASKS + t] = red2[0][t] + red2[1][t] + red2[2][t] + red2[3][t] + cb3[t];
}

// ---------------- host ----------------

extern "C" void kernel_launch(void* const* d_in, const int* in_sizes, int n_in,
                              void* d_out, int out_size, void* d_ws, size_t ws_size,
                              hipStream_t stream) {
  const float* x      = (const float*)d_in[0];
  const int*   ei     = (const int*)d_in[1];
  const int*   batch  = (const int*)d_in[2];
  const float* w1_0   = (const float*)d_in[3];
  const float* b1_0   = (const float*)d_in[4];
  const float* w2_0   = (const float*)d_in[5];
  const float* b2_0   = (const float*)d_in[6];
  const float* w1_r   = (const float*)d_in[7];
  const float* b1_r   = (const float*)d_in[8];
  const float* w2_r   = (const float*)d_in[9];
  const float* b2_r   = (const float*)d_in[10];
  const float* cw1    = (const float*)d_in[11];
  const float* cb1    = (const float*)d_in[12];
  const float* cw2    = (const float*)d_in[13];
  const float* cb2    = (const float*)d_in[14];
  const float* cw3    = (const float*)d_in[15];
  const float* cb3    = (const float*)d_in[16];
  float* out = (float*)d_out;

  const int* e_src = ei;
  const int* e_dst = ei + N_EDGES;

  const size_t HBUF = (size_t)MPAD * HPAD;
  const size_t ZBUF = (size_t)MPAD * K0PAD;
  const size_t WT   = (size_t)HPAD * HPAD;
  const int NB = (N_NODES + 255) / 256;

  unsigned short* hA  = (unsigned short*)d_ws;
  unsigned short* hB  = hA + HBUF;
  unsigned short* hC  = hB + HBUF;
  unsigned short* z0  = hC + HBUF;
  unsigned short* xb  = z0 + ZBUF;
  unsigned short* wt0 = xb + ZBUF;
  unsigned short* wts = wt0 + (size_t)HPAD * K0PAD;
  float* biases = (float*)(wts + 9 * WT);
  int* row_ptr  = (int*)(biases + 10 * HPAD);
  int* counts   = row_ptr + (N_NODES + 1);
  int* edge_src = counts + N_NODES;
  int* gptr     = edge_src + N_EDGES;
  int* gcnt     = gptr + (NUM_GRAPHS + 1);
  int* partials = gcnt + NUM_GRAPHS;
  int* poff     = partials + (NB + 1);

  hipMemsetAsync(counts, 0, N_NODES * sizeof(int), stream);
  hipMemsetAsync(gcnt, 0, NUM_GRAPHS * sizeof(int), stream);
  {
    int total = HPAD * K0PAD + 10 * HPAD + MPAD * K0PAD + N_EDGES + N_NODES;
    k_setup<<<(total + 255) / 256, 256, 0, stream>>>(
        w1_0, b1_0, b2_0, b1_r, b2_r, x, e_dst, batch, wt0, biases, xb, counts, gcnt);
  }
  k_wt_tiled<<<9 * 100, 256, 0, stream>>>(w2_0, w1_r, w2_r, wts);

  k_scan1<<<NB, 256, 0, stream>>>(counts, partials, N_NODES);
  k_exscan<<<1, 1024, 0, stream>>>(partials, poff, nullptr, NB);
  k_scan3<<<NB, 256, 0, stream>>>(counts, poff, row_ptr, counts, N_NODES);
  k_scatter<<<(N_EDGES + 255) / 256, 256, 0, stream>>>(e_src, e_dst, counts, edge_src, N_EDGES);
  k_exscan<<<1, 1024, 0, stream>>>(gcnt, gptr, nullptr, NUM_GRAPHS);

  const int G16 = (MPAD / 128) * (HPAD / 128);  // 1180
  const int GW  = MPAD / 128;                   // 236
  const int GY = HPAD / 128;

  // ---- layer 0 (control) ----
  k_agg_bf16<K0PAD / 2><<<(N_NODES + 3) / 4, 256, 0, stream>>>(
      (const unsigned int*)xb, row_ptr, edge_src, (unsigned int*)z0, N_NODES);
  k_mgemm<<<G16, 512, 0, stream>>>(z0, wt0, biases + 0 * HPAD, hC, K0PAD, K0PAD, HPAD, K0PAD, 1, GY);
  k_mgemm<<<G16, 512, 0, stream>>>(hC, wts, biases + 1 * HPAD, hA, HPAD, HPAD, HPAD, HPAD, 1, GY);

  // ---- layers 1..4: A/B — layers 1,2 control; layers 3,4 wide ----
  unsigned short* h = hA;
  unsigned short* z = hB;
  unsigned short* tb = hC;
  for (int i = 0; i < 4; ++i) {
    k_agg_bf16<HPAD / 2><<<(N_NODES + 3) / 4, 256, 0, stream>>>(
        (const unsigned int*)h, row_ptr, edge_src, (unsigned int*)z, N_NODES);
    if (i < 2) {
      k_mgemm<<<G16, 512, 0, stream>>>(z, wts + (1 + (size_t)i) * WT, biases + (2 + i) * HPAD, tb,
                                       HPAD, HPAD, HPAD, HPAD, 1, GY);
      k_mgemm<<<G16, 512, 0, stream>>>(tb, wts + (5 + (size_t)i) * WT, biases + (6 + i) * HPAD, z,
                                       HPAD, HPAD, HPAD, HPAD, 1, GY);
    } else {
      k_mgemm_wide<<<GW, 512, 0, stream>>>(z, wts + (1 + (size_t)i) * WT, biases + (2 + i) * HPAD, tb,
                                           HPAD, HPAD, HPAD, HPAD, 1);
      k_mgemm_wide<<<GW, 512, 0, stream>>>(tb, wts + (5 + (size_t)i) * WT, biases + (6 + i) * HPAD, z,
                                           HPAD, HPAD, HPAD, HPAD, (i < 3) ? 1 : 0);
    }
    unsigned short* tmp = h; h = z; z = tmp;
  }

  k_poolcls<<<NUM_GRAPHS, 256, 0, stream>>>((const unsigned int*)h, gptr,
                                            cw1, cb1, cw2, cb2, cw3, cb3, out);
}

// Round 15
// 706.470 us; speedup vs baseline: 1.0139x; 1.0139x over previous
//
#include <hip/hip_runtime.h>

#define N_NODES 30000
#define N_EDGES 300000
#define NUM_GRAPHS 512
#define HID 600
#define IN_FEATS 9
#define NUM_TASKS 128

#define MPAD 30208          // 236 * 128
#define HPAD 640
#define K0PAD 32

typedef __attribute__((ext_vector_type(4))) float f32x4;
typedef __attribute__((ext_vector_type(8))) short bf16x8;

// ---------------- bf16 helpers ----------------

__device__ __forceinline__ float bflo(unsigned int v) {
  union { unsigned int u; float f; } c; c.u = v << 16; return c.f;
}
__device__ __forceinline__ float bfhi(unsigned int v) {
  union { unsigned int u; float f; } c; c.u = v & 0xffff0000u; return c.f;
}
__device__ __forceinline__ unsigned short f2bf(float f) {
  union { float f; unsigned int u; } c; c.f = f;
  unsigned int u = c.u;
  return (unsigned short)((u + 0x7fffu + ((u >> 16) & 1u)) >> 16);
}
__device__ __forceinline__ unsigned int pack2(float a, float b) {
  return (unsigned int)f2bf(a) | ((unsigned int)f2bf(b) << 16);
}

// ---------------- fused setup: wt0 | biases | xconv | hist(dst) | hist(batch) ----------------

__global__ void k_setup(const float* __restrict__ w1_0,
                        const float* __restrict__ b1_0, const float* __restrict__ b2_0,
                        const float* __restrict__ b1_r, const float* __restrict__ b2_r,
                        const float* __restrict__ x,
                        const int* __restrict__ e_dst, const int* __restrict__ batch,
                        unsigned short* __restrict__ wt0, float* __restrict__ biases,
                        unsigned short* __restrict__ xb,
                        int* __restrict__ counts, int* __restrict__ gcnt) {
  const int S0 = HPAD * K0PAD;
  const int S1 = 10 * HPAD;
  const int S2 = MPAD * K0PAD;
  const int S3 = N_EDGES;
  int idx = blockIdx.x * 256 + threadIdx.x;
  if (idx < S0) {
    int n = idx / K0PAD, k = idx % K0PAD;
    float v = (n < HID && k < IN_FEATS) ? w1_0[(size_t)k * HID + n] : 0.f;
    wt0[idx] = f2bf(v);
    return;
  }
  idx -= S0;
  if (idx < S1) {
    int w = idx / HPAD, i = idx % HPAD;
    float v = 0.f;
    if (i < HID) {
      if (w == 0) v = b1_0[i];
      else if (w == 1) v = b2_0[i];
      else if (w < 6) v = b1_r[(size_t)(w - 2) * HID + i];
      else v = b2_r[(size_t)(w - 6) * HID + i];
    }
    biases[idx] = v;
    return;
  }
  idx -= S1;
  if (idx < S2) {
    int m = idx >> 5, k = idx & 31;
    float v = (m < N_NODES && k < IN_FEATS) ? x[(size_t)m * IN_FEATS + k] : 0.f;
    xb[idx] = f2bf(v);
    return;
  }
  idx -= S2;
  if (idx < S3) {
    atomicAdd(&counts[e_dst[idx]], 1);
    return;
  }
  idx -= S3;
  if (idx < N_NODES) {
    atomicAdd(&gcnt[batch[idx]], 1);
  }
}

// ---------------- CSR scan (last block also exscans gcnt->gptr) ----------------

__global__ __launch_bounds__(256) void k_scan1(const int* __restrict__ in,
                                               int* __restrict__ partials, int n,
                                               const int* __restrict__ gcnt,
                                               int* __restrict__ gptr) {
  __shared__ int buf[256];
  int t = threadIdx.x;
  if (blockIdx.x == gridDim.x - 1) {
    // exclusive scan of gcnt[512] -> gptr[513]
    int v0 = gcnt[2 * t], v1 = gcnt[2 * t + 1];
    buf[t] = v0 + v1;
    __syncthreads();
    for (int off = 1; off < 256; off <<= 1) {
      int x = (t >= off) ? buf[t - off] : 0;
      __syncthreads();
      buf[t] += x;
      __syncthreads();
    }
    int pre = (t == 0) ? 0 : buf[t - 1];
    gptr[2 * t] = pre;
    gptr[2 * t + 1] = pre + v0;
    if (t == 255) gptr[512] = pre + v0 + v1;
    return;
  }
  int i = blockIdx.x * 256 + t;
  buf[t] = (i < n) ? in[i] : 0;
  __syncthreads();
  for (int off = 128; off; off >>= 1) {
    if (t < off) buf[t] += buf[t + off];
    __syncthreads();
  }
  if (t == 0) partials[blockIdx.x] = buf[0];
}

__global__ __launch_bounds__(1024) void k_exscan(const int* __restrict__ in,
                                                 int* __restrict__ out, int n) {
  __shared__ int buf[1024];
  int tid = threadIdx.x;
  int CH = (n + 1023) / 1024;
  int base = tid * CH;
  int s = 0;
  for (int j = 0; j < CH; ++j) {
    int i = base + j;
    if (i < n) s += in[i];
  }
  buf[tid] = s;
  __syncthreads();
  for (int off = 1; off < 1024; off <<= 1) {
    int t = (tid >= off) ? buf[tid - off] : 0;
    __syncthreads();
    buf[tid] += t;
    __syncthreads();
  }
  int pre = (tid == 0) ? 0 : buf[tid - 1];
  for (int j = 0; j < CH; ++j) {
    int i = base + j;
    if (i <= n) out[i] = pre;
    if (i < n) pre += in[i];
  }
}

__global__ __launch_bounds__(256) void k_scan3(const int* __restrict__ in,
                                               const int* __restrict__ poff,
                                               int* __restrict__ out,
                                               int* __restrict__ cursor, int n) {
  __shared__ int buf[256];
  int b = blockIdx.x, t = threadIdx.x;
  int i = b * 256 + t;
  int v = (i < n) ? in[i] : 0;
  buf[t] = v;
  __syncthreads();
  for (int off = 1; off < 256; off <<= 1) {
    int x = (t >= off) ? buf[t - off] : 0;
    __syncthreads();
    buf[t] += x;
    __syncthreads();
  }
  int base = poff[b];
  int excl = base + buf[t] - v;
  if (i < n) {
    out[i] = excl;
    cursor[i] = excl;
    if (i == n - 1) out[n] = base + buf[t];
  }
}

__global__ void k_scatter(const int* __restrict__ src, const int* __restrict__ dst,
                          int* __restrict__ cursor, int* __restrict__ edge_src, int E) {
  int e = blockIdx.x * blockDim.x + threadIdx.x;
  if (e < E) {
    int pos = atomicAdd(&cursor[dst[e]], 1);
    edge_src[pos] = src[e];
  }
}

// ---------------- big-weight transpose ----------------

__global__ __launch_bounds__(256) void k_wt_tiled(
    const float* __restrict__ w2_0, const float* __restrict__ w1_r,
    const float* __restrict__ w2_r, unsigned short* __restrict__ wts) {
  __shared__ float tile[64][65];
  int b = blockIdx.x;
  int w = b / 100;
  int tb = b % 100;
  int tn = (tb % 10) * 64;
  int tk = (tb / 10) * 64;
  const float* W;
  if (w == 0) W = w2_0;
  else if (w < 5) W = w1_r + (size_t)(w - 1) * HID * HID;
  else W = w2_r + (size_t)(w - 5) * HID * HID;
  int t = threadIdx.x;
  int lx = t & 63, ly = t >> 6;
#pragma unroll
  for (int i = 0; i < 16; ++i) {
    int k = tk + ly + i * 4;
    int n = tn + lx;
    float v = (k < HID && n < HID) ? W[(size_t)k * HID + n] : 0.f;
    tile[ly + i * 4][lx] = v;
  }
  __syncthreads();
  unsigned short* dst = wts + (size_t)w * HPAD * HPAD;
#pragma unroll
  for (int i = 0; i < 16; ++i) {
    int n = tn + ly + i * 4;
    int k = tk + lx;
    dst[(size_t)n * HPAD + k] = f2bf(tile[lx][ly + i * 4]);
  }
}

// ---------------- aggregation: full-row wave-per-node ----------------

template <int U>
__global__ __launch_bounds__(256) void k_agg_bf16(
    const unsigned int* __restrict__ h, const int* __restrict__ ptr,
    const int* __restrict__ esrc, unsigned int* __restrict__ z, int n_nodes) {
  int wave = threadIdx.x >> 6, lane = threadIdx.x & 63;
  int node = blockIdx.x * 4 + wave;
  if (node >= n_nodes) return;
  int beg = ptr[node], end = ptr[node + 1];
  const unsigned int* hn = h + (size_t)node * U;
  float a0[5], a1[5];
#pragma unroll
  for (int i = 0; i < 5; ++i) {
    int u = lane + i * 64;
    if (u < U) { unsigned int v = hn[u]; a0[i] = bflo(v); a1[i] = bfhi(v); }
    else { a0[i] = 0.f; a1[i] = 0.f; }
  }
  int e = beg;
  for (; e + 4 <= end; e += 4) {
    const unsigned int* p0 = h + (size_t)esrc[e] * U;
    const unsigned int* p1 = h + (size_t)esrc[e + 1] * U;
    const unsigned int* p2 = h + (size_t)esrc[e + 2] * U;
    const unsigned int* p3 = h + (size_t)esrc[e + 3] * U;
    unsigned int v0[5], v1[5], v2[5], v3[5];
#pragma unroll
    for (int i = 0; i < 5; ++i) {
      int u = lane + i * 64;
      if (u < U) { v0[i] = p0[u]; v1[i] = p1[u]; v2[i] = p2[u]; v3[i] = p3[u]; }
      else { v0[i] = 0; v1[i] = 0; v2[i] = 0; v3[i] = 0; }
    }
#pragma unroll
    for (int i = 0; i < 5; ++i) {
      a0[i] += (bflo(v0[i]) + bflo(v1[i])) + (bflo(v2[i]) + bflo(v3[i]));
      a1[i] += (bfhi(v0[i]) + bfhi(v1[i])) + (bfhi(v2[i]) + bfhi(v3[i]));
    }
  }
  for (; e < end; ++e) {
    const unsigned int* p0 = h + (size_t)esrc[e] * U;
#pragma unroll
    for (int i = 0; i < 5; ++i) {
      int u = lane + i * 64;
      if (u < U) { unsigned int v = p0[u]; a0[i] += bflo(v); a1[i] += bfhi(v); }
    }
  }
  unsigned int* zn = z + (size_t)node * U;
#pragma unroll
  for (int i = 0; i < 5; ++i) {
    int u = lane + i * 64;
    if (u < U) zn[u] = pack2(a0[i], a1[i]);
  }
}

// ---------------- GEMM (R13/R11 best): 128x128, 8 waves, 24 waves/CU ----------------

#define GLOAD(gptr, lptr)                                                            \
  __builtin_amdgcn_global_load_lds(                                                  \
      (const __attribute__((address_space(1))) unsigned int*)(gptr),                 \
      (__attribute__((address_space(3))) unsigned int*)(lptr), 16, 0, 0)

__global__ __launch_bounds__(512, 6) void k_mgemm(
    const unsigned short* __restrict__ A, const unsigned short* __restrict__ Bt,
    const float* __restrict__ bias, unsigned short* __restrict__ C,
    int lda, int ldb, int ldc, int K, int relu, int gy) {
  // bijective XCD-chunked swizzle (m204)
  int G = gridDim.x;
  int orig = blockIdx.x;
  int q = G >> 3, r = G & 7;
  int xcd = orig & 7, local = orig >> 3;
  int wgid = (xcd < r ? xcd * (q + 1) : r * (q + 1) + (xcd - r) * q) + local;
  int n0 = (wgid % gy) * 128;
  int m0 = (wgid / gy) * 128;

  __shared__ unsigned short smem[3 * 4096 * 2];   // 48 KB: As[3] | Bs[3]; reused for C-stage
  unsigned short* Asb = smem;
  unsigned short* Bsb = smem + 12288;

  int t = threadIdx.x;
  int lane = t & 63, wave = t >> 6;
  int wm = (wave >> 2) * 64;
  int wn = (wave & 3) * 32;

  f32x4 acc[4][2] = {};

  int off = t * 8;
  int rm = off >> 5, rk = off & 31;

  const unsigned short* Ar = A + (size_t)(m0 + rm) * lda + rk;
  const unsigned short* Br = Bt + (size_t)(n0 + rm) * ldb + rk;

  int nt = K >> 5;
  GLOAD(Ar, Asb + off);
  GLOAD(Br, Bsb + off);
  if (nt > 1) {
    GLOAD(Ar + 32, Asb + 4096 + off);
    GLOAD(Br + 32, Bsb + 4096 + off);
  }

  int kk = (lane >> 4) * 8;
  int ra = wm + (lane & 15);
  int rb = wn + (lane & 15);
  int cur = 0;

  for (int tt = 0; tt < nt; ++tt) {
    if (tt + 1 < nt) {
      asm volatile("s_waitcnt vmcnt(2)" ::: "memory");
    } else {
      asm volatile("s_waitcnt vmcnt(0)" ::: "memory");
    }
    __builtin_amdgcn_s_barrier();
    if (tt + 2 < nt) {
      int k2 = (tt + 2) << 5;
      int nb = cur + 2; if (nb >= 3) nb -= 3;
      GLOAD(Ar + k2, Asb + nb * 4096 + off);
      GLOAD(Br + k2, Bsb + nb * 4096 + off);
    }
    bf16x8 a[4], b[2];
#pragma unroll
    for (int i = 0; i < 4; ++i)
      a[i] = *(const bf16x8*)(Asb + cur * 4096 + (ra + i * 16) * 32 + kk);
#pragma unroll
    for (int j = 0; j < 2; ++j)
      b[j] = *(const bf16x8*)(Bsb + cur * 4096 + (rb + j * 16) * 32 + kk);
#pragma unroll
    for (int i = 0; i < 4; ++i)
#pragma unroll
      for (int j = 0; j < 2; ++j)
        acc[i][j] = __builtin_amdgcn_mfma_f32_16x16x32_bf16(b[j], a[i], acc[i][j], 0, 0, 0);
    cur += 1; if (cur >= 3) cur = 0;
  }

  // epilogue: bias+relu in reg, stage C tile through LDS (swizzled), coalesced 16B stores
  __syncthreads();
  int colm = lane & 15;
  int nq = (lane >> 4) * 4;
#pragma unroll
  for (int j = 0; j < 2; ++j) {
    int nloc = wn + j * 16 + nq;
    f32x4 bv = *(const f32x4*)&bias[n0 + nloc];
#pragma unroll
    for (int i = 0; i < 4; ++i) {
      int mloc = wm + i * 16 + colm;
      float v0 = acc[i][j][0] + bv[0];
      float v1 = acc[i][j][1] + bv[1];
      float v2 = acc[i][j][2] + bv[2];
      float v3 = acc[i][j][3] + bv[3];
      if (relu) {
        v0 = fmaxf(v0, 0.f); v1 = fmaxf(v1, 0.f);
        v2 = fmaxf(v2, 0.f); v3 = fmaxf(v3, 0.f);
      }
      uint2 w;
      w.x = pack2(v0, v1);
      w.y = pack2(v2, v3);
      int nblk = (nloc >> 2) ^ ((mloc & 7) << 2);
      *(uint2*)&smem[mloc * 128 + nblk * 4] = w;
    }
  }
  __syncthreads();
#pragma unroll
  for (int p = 0; p < 4; ++p) {
    int idx = p * 4096 + t * 8;
    int mloc = idx >> 7;
    int ncol = idx & 127;
    int s = (mloc & 7) << 2;
    int nb0 = (ncol >> 2) ^ s;
    int nb1 = ((ncol >> 2) + 1) ^ s;
    uint2 w0 = *(uint2*)&smem[mloc * 128 + nb0 * 4];
    uint2 w1 = *(uint2*)&smem[mloc * 128 + nb1 * 4];
    uint4 w;
    w.x = w0.x; w.y = w0.y; w.z = w1.x; w.w = w1.y;
    *(uint4*)&C[(size_t)(m0 + mloc) * ldc + n0 + ncol] = w;
  }
}

// ---------------- fused pool + classifier ----------------

__global__ __launch_bounds__(256) void k_poolcls(
    const unsigned int* __restrict__ h, const int* __restrict__ gptr,
    const float* __restrict__ cw1, const float* __restrict__ cb1,
    const float* __restrict__ cw2, const float* __restrict__ cb2,
    const float* __restrict__ cw3, const float* __restrict__ cb3,
    float* __restrict__ out) {
  const int U = HPAD / 2;
  __shared__ float red[4][HPAD];
  __shared__ float f[HPAD];
  __shared__ float red2[4][256];
  __shared__ float z1[256];
  __shared__ float z2[256];
  int g = blockIdx.x;
  int t = threadIdx.x;
  int wave = t >> 6, lane = t & 63;
  int beg = gptr[g], end = gptr[g + 1];

  {
    float a0[5] = {0.f, 0.f, 0.f, 0.f, 0.f}, a1[5] = {0.f, 0.f, 0.f, 0.f, 0.f};
    for (int i = beg + wave; i < end; i += 4) {
      const unsigned int* hi = h + (size_t)i * U;
#pragma unroll
      for (int j = 0; j < 5; ++j) {
        unsigned int v = hi[lane + j * 64];
        a0[j] += bflo(v); a1[j] += bfhi(v);
      }
    }
#pragma unroll
    for (int j = 0; j < 5; ++j) {
      int u = lane + j * 64;
      red[wave][2 * u] = a0[j];
      red[wave][2 * u + 1] = a1[j];
    }
  }
  __syncthreads();
  for (int c = t; c < HPAD; c += 256)
    f[c] = red[0][c] + red[1][c] + red[2][c] + red[3][c];
  __syncthreads();

  {
    float acc[4] = {0.f, 0.f, 0.f, 0.f};
    int k0 = wave * 150, k1 = k0 + 150;
    for (int k = k0; k < k1; ++k) {
      float fv = f[k];
      const float* row = cw1 + (size_t)k * 256;
#pragma unroll
      for (int j = 0; j < 4; ++j) acc[j] += fv * row[lane + j * 64];
    }
#pragma unroll
    for (int j = 0; j < 4; ++j) red2[wave][lane + j * 64] = acc[j];
  }
  __syncthreads();
  z1[t] = fmaxf(red2[0][t] + red2[1][t] + red2[2][t] + red2[3][t] + cb1[t], 0.f);
  __syncthreads();

  {
    float acc[4] = {0.f, 0.f, 0.f, 0.f};
    int k0 = wave * 64, k1 = k0 + 64;
    for (int k = k0; k < k1; ++k) {
      float zv = z1[k];
      const float* row = cw2 + (size_t)k * 256;
#pragma unroll
      for (int j = 0; j < 4; ++j) acc[j] += zv * row[lane + j * 64];
    }
    __syncthreads();
#pragma unroll
    for (int j = 0; j < 4; ++j) red2[wave][lane + j * 64] = acc[j];
  }
  __syncthreads();
  z2[t] = fmaxf(red2[0][t] + red2[1][t] + red2[2][t] + red2[3][t] + cb2[t], 0.f);
  __syncthreads();

  {
    float a0 = 0.f, a1 = 0.f;
    int k0 = wave * 64, k1 = k0 + 64;
    for (int k = k0; k < k1; ++k) {
      float zv = z2[k];
      const float* row = cw3 + (size_t)k * NUM_TASKS;
      a0 += zv * row[lane];
      a1 += zv * row[lane + 64];
    }
    __syncthreads();
    red2[wave][lane] = a0;
    red2[wave][lane + 64] = a1;
  }
  __syncthreads();
  if (t < NUM_TASKS)
    out[(size_t)g * NUM_TASKS + t] = red2[0][t] + red2[1][t] + red2[2][t] + red2[3][t] + cb3[t];
}

// ---------------- host ----------------

extern "C" void kernel_launch(void* const* d_in, const int* in_sizes, int n_in,
                              void* d_out, int out_size, void* d_ws, size_t ws_size,
                              hipStream_t stream) {
  const float* x      = (const float*)d_in[0];
  const int*   ei     = (const int*)d_in[1];
  const int*   batch  = (const int*)d_in[2];
  const float* w1_0   = (const float*)d_in[3];
  const float* b1_0   = (const float*)d_in[4];
  const float* w2_0   = (const float*)d_in[5];
  const float* b2_0   = (const float*)d_in[6];
  const float* w1_r   = (const float*)d_in[7];
  const float* b1_r   = (const float*)d_in[8];
  const float* w2_r   = (const float*)d_in[9];
  const float* b2_r   = (const float*)d_in[10];
  const float* cw1    = (const float*)d_in[11];
  const float* cb1    = (const float*)d_in[12];
  const float* cw2    = (const float*)d_in[13];
  const float* cb2    = (const float*)d_in[14];
  const float* cw3    = (const float*)d_in[15];
  const float* cb3    = (const float*)d_in[16];
  float* out = (float*)d_out;

  const int* e_src = ei;
  const int* e_dst = ei + N_EDGES;

  const size_t HBUF = (size_t)MPAD * HPAD;
  const size_t ZBUF = (size_t)MPAD * K0PAD;
  const size_t WT   = (size_t)HPAD * HPAD;
  const int NB = (N_NODES + 255) / 256;  // 118

  unsigned short* hA  = (unsigned short*)d_ws;
  unsigned short* hB  = hA + HBUF;
  unsigned short* hC  = hB + HBUF;
  unsigned short* z0  = hC + HBUF;
  unsigned short* xb  = z0 + ZBUF;
  unsigned short* wt0 = xb + ZBUF;
  unsigned short* wts = wt0 + (size_t)HPAD * K0PAD;
  float* biases = (float*)(wts + 9 * WT);
  int* row_ptr  = (int*)(biases + 10 * HPAD);
  int* counts   = row_ptr + (N_NODES + 1);
  int* edge_src = counts + N_NODES;
  int* gptr     = edge_src + N_EDGES;
  int* gcnt     = gptr + (NUM_GRAPHS + 1);
  int* partials = gcnt + NUM_GRAPHS;
  int* poff     = partials + (NB + 1);

  // ---- fused setup (conversions + both histograms) ----
  hipMemsetAsync(counts, 0, N_NODES * sizeof(int), stream);
  hipMemsetAsync(gcnt, 0, NUM_GRAPHS * sizeof(int), stream);
  {
    int total = HPAD * K0PAD + 10 * HPAD + MPAD * K0PAD + N_EDGES + N_NODES;
    k_setup<<<(total + 255) / 256, 256, 0, stream>>>(
        w1_0, b1_0, b2_0, b1_r, b2_r, x, e_dst, batch, wt0, biases, xb, counts, gcnt);
  }
  k_wt_tiled<<<9 * 100, 256, 0, stream>>>(w2_0, w1_r, w2_r, wts);

  // ---- CSR (k_scan1's extra block also produces gptr) ----
  k_scan1<<<NB + 1, 256, 0, stream>>>(counts, partials, N_NODES, gcnt, gptr);
  k_exscan<<<1, 1024, 0, stream>>>(partials, poff, NB);
  k_scan3<<<NB, 256, 0, stream>>>(counts, poff, row_ptr, counts, N_NODES);
  k_scatter<<<(N_EDGES + 255) / 256, 256, 0, stream>>>(e_src, e_dst, counts, edge_src, N_EDGES);

  const int G16 = (MPAD / 128) * (HPAD / 128);  // 1180
  const int GY = HPAD / 128;                    // 5

  // ---- layer 0 ----
  k_agg_bf16<K0PAD / 2><<<(N_NODES + 3) / 4, 256, 0, stream>>>(
      (const unsigned int*)xb, row_ptr, edge_src, (unsigned int*)z0, N_NODES);
  k_mgemm<<<G16, 512, 0, stream>>>(z0, wt0, biases + 0 * HPAD, hC, K0PAD, K0PAD, HPAD, K0PAD, 1, GY);
  k_mgemm<<<G16, 512, 0, stream>>>(hC, wts, biases + 1 * HPAD, hA, HPAD, HPAD, HPAD, HPAD, 1, GY);

  // ---- layers 1..4 ----
  unsigned short* h = hA;
  unsigned short* z = hB;
  unsigned short* tb = hC;
  for (int i = 0; i < 4; ++i) {
    k_agg_bf16<HPAD / 2><<<(N_NODES + 3) / 4, 256, 0, stream>>>(
        (const unsigned int*)h, row_ptr, edge_src, (unsigned int*)z, N_NODES);
    k_mgemm<<<G16, 512, 0, stream>>>(z, wts + (1 + (size_t)i) * WT, biases + (2 + i) * HPAD, tb,
                                     HPAD, HPAD, HPAD, HPAD, 1, GY);
    k_mgemm<<<G16, 512, 0, stream>>>(tb, wts + (5 + (size_t)i) * WT, biases + (6 + i) * HPAD, z,
                                     HPAD, HPAD, HPAD, HPAD, (i < 3) ? 1 : 0, GY);
    unsigned short* tmp = h; h = z; z = tmp;
  }

  // ---- fused pool + classifier ----
  k_poolcls<<<NUM_GRAPHS, 256, 0, stream>>>((const unsigned int*)h, gptr,
                                            cw1, cb1, cw2, cb2, cw3, cb3, out);
}